// Round 1
// baseline (289.426 us; speedup 1.0000x reference)
//
#include <hip/hip_runtime.h>

#define IMAGE 224
#define PAD   30
#define CROP  164   // IMAGE - 2*PAD
#define BATCH 16
#define TT    16
#define W4    56    // IMAGE/4

__global__ __launch_bounds__(256) void prompt_add_kernel(
    const float* __restrict__ x,
    const float* __restrict__ pu1,  const float* __restrict__ pu10,
    const float* __restrict__ pd1,  const float* __restrict__ pd10,
    const float* __restrict__ pl1,  const float* __restrict__ pl10,
    const float* __restrict__ pr1,  const float* __restrict__ pr10,
    const int* __restrict__ cam_idx,
    const int* __restrict__ off_right,
    const int* __restrict__ off_down,
    float* __restrict__ out)
{
    const int idx = blockIdx.x * blockDim.x + threadIdx.x;
    const int total = BATCH * 3 * IMAGE * W4;
    if (idx >= total) return;

    const int w4 = idx % W4;
    const int h  = (idx / W4) % IMAGE;
    const int c  = (idx / (W4 * IMAGE)) % 3;
    const int b  =  idx / (W4 * IMAGE * 3);

    const int ci    = cam_idx[b];
    const int orr   = off_right[b];
    const int od    = off_down[b];
    const int off_l = 2 * PAD - orr;
    const int off_u = 2 * PAD - od;
    const int n10_l = off_l / 10;
    const int n10_u = off_u / 10;
    const int n1_r  = orr % 10;
    const int n1_d  = od % 10;

    const int w0      = w4 * 4;
    const int base_cc = ci * 3 + c;   // camera*3 + channel

    float p[4];

    if (h < off_u) {
        // --- top band: row taken from pad_up_{10,1}, w-parallel ---
        const float* rowp = (h < n10_u * 10)
            ? (pu10 + (size_t)(base_cc * 10 + (h % 10)) * IMAGE)
            : (pu1  + (size_t)base_cc * IMAGE);
        #pragma unroll
        for (int j = 0; j < 4; ++j) p[j] = rowp[w0 + j];
    } else if (h >= IMAGE - od) {
        // --- bottom band: row from pad_down_{1,10} ---
        const int hd = h - (IMAGE - od);          // >= 0
        const float* rowp = (hd < n1_d)
            ? (pd1  + (size_t)base_cc * IMAGE)
            : (pd10 + (size_t)(base_cc * 10 + ((hd - n1_d) % 10)) * IMAGE);
        #pragma unroll
        for (int j = 0; j < 4; ++j) p[j] = rowp[w0 + j];
    } else {
        // --- middle band: left / zero / right per-w ---
        int r = h - off_u;
        r = r < 0 ? 0 : (r > CROP - 1 ? CROP - 1 : r);
        #pragma unroll
        for (int j = 0; j < 4; ++j) {
            const int w = w0 + j;
            float v;
            if (w < off_l) {
                v = (w < n10_l * 10)
                    ? pl10[((size_t)base_cc * CROP + r) * 10 + (w % 10)]
                    : pl1 [ (size_t)base_cc * CROP + r];
            } else if (w >= IMAGE - orr) {
                const int wd = w - (IMAGE - orr);  // >= 0
                v = (wd < n1_r)
                    ? pr1 [ (size_t)base_cc * CROP + r]
                    : pr10[((size_t)base_cc * CROP + r) * 10 + ((wd - n1_r) % 10)];
            } else {
                v = 0.0f;
            }
            p[j] = v;
        }
    }

    const float4 pv = make_float4(p[0], p[1], p[2], p[3]);
    // x index: (((b*3 + c)*TT + t)*IMAGE + h)*IMAGE + w0
    const size_t plane = (size_t)IMAGE * IMAGE;
    const size_t base  = ((size_t)(b * 3 + c) * TT) * plane + (size_t)h * IMAGE + w0;

    #pragma unroll
    for (int t = 0; t < TT; ++t) {
        const size_t off = base + (size_t)t * plane;
        const float4 xv = *reinterpret_cast<const float4*>(x + off);
        float4 ov;
        ov.x = xv.x + pv.x;
        ov.y = xv.y + pv.y;
        ov.z = xv.z + pv.z;
        ov.w = xv.w + pv.w;
        *reinterpret_cast<float4*>(out + off) = ov;
    }
}

extern "C" void kernel_launch(void* const* d_in, const int* in_sizes, int n_in,
                              void* d_out, int out_size, void* d_ws, size_t ws_size,
                              hipStream_t stream) {
    const float* x    = (const float*)d_in[0];
    const float* pu1  = (const float*)d_in[1];
    const float* pu10 = (const float*)d_in[2];
    const float* pd1  = (const float*)d_in[3];
    const float* pd10 = (const float*)d_in[4];
    const float* pl1  = (const float*)d_in[5];
    const float* pl10 = (const float*)d_in[6];
    const float* pr1  = (const float*)d_in[7];
    const float* pr10 = (const float*)d_in[8];
    const int* cam_idx   = (const int*)d_in[9];
    const int* off_right = (const int*)d_in[10];
    const int* off_down  = (const int*)d_in[11];
    float* out = (float*)d_out;

    const int total  = BATCH * 3 * IMAGE * W4;   // 602112 threads
    const int block  = 256;
    const int grid   = (total + block - 1) / block;

    prompt_add_kernel<<<grid, block, 0, stream>>>(
        x, pu1, pu10, pd1, pd10, pl1, pl10, pr1, pr10,
        cam_idx, off_right, off_down, out);
}

// Round 2
// 275.577 us; speedup vs baseline: 1.0503x; 1.0503x over previous
//
#include <hip/hip_runtime.h>

#define IMAGE 224
#define PAD   30
#define CROP  164   // IMAGE - 2*PAD
#define BATCH 16
#define TT    16
#define W4    56    // IMAGE/4

// One thread per float4 of the OUTPUT tensor (b,c,t,h,w0..w0+3).
// Thread index == flat float4 index, so global access is perfectly coalesced
// and every wave does exactly one independent load+add+store (max TLP,
// no per-thread dependent chain -- this is what was capping us at 31% BW).
__global__ __launch_bounds__(256) void prompt_add_kernel(
    const float* __restrict__ x,
    const float* __restrict__ pu1,  const float* __restrict__ pu10,
    const float* __restrict__ pd1,  const float* __restrict__ pd10,
    const float* __restrict__ pl1,  const float* __restrict__ pl10,
    const float* __restrict__ pr1,  const float* __restrict__ pr10,
    const int* __restrict__ cam_idx,
    const int* __restrict__ off_right,
    const int* __restrict__ off_down,
    float* __restrict__ out)
{
    const int idx = blockIdx.x * blockDim.x + threadIdx.x;
    const int total = BATCH * 3 * TT * IMAGE * W4;   // 9,633,792
    if (idx >= total) return;

    const int w4 = idx % W4;
    const int h  = (idx / W4) % IMAGE;
    // t is implicit in idx; prompt depends only on (b,c,h,w)
    const int c  = (idx / (W4 * IMAGE * TT)) % 3;
    const int b  =  idx / (W4 * IMAGE * TT * 3);

    const int ci    = cam_idx[b];
    const int orr   = off_right[b];
    const int od    = off_down[b];
    const int off_l = 2 * PAD - orr;
    const int off_u = 2 * PAD - od;
    const int n10_l = off_l / 10;
    const int n10_u = off_u / 10;
    const int n1_r  = orr % 10;
    const int n1_d  = od % 10;

    const int w0      = w4 * 4;
    const int base_cc = ci * 3 + c;   // camera*3 + channel

    float p[4];

    if (h < off_u) {
        // --- top band: row taken from pad_up_{10,1} ---
        const float* rowp = (h < n10_u * 10)
            ? (pu10 + (size_t)(base_cc * 10 + (h % 10)) * IMAGE)
            : (pu1  + (size_t)base_cc * IMAGE);
        #pragma unroll
        for (int j = 0; j < 4; ++j) p[j] = rowp[w0 + j];
    } else if (h >= IMAGE - od) {
        // --- bottom band: row from pad_down_{1,10} ---
        const int hd = h - (IMAGE - od);          // >= 0
        const float* rowp = (hd < n1_d)
            ? (pd1  + (size_t)base_cc * IMAGE)
            : (pd10 + (size_t)(base_cc * 10 + ((hd - n1_d) % 10)) * IMAGE);
        #pragma unroll
        for (int j = 0; j < 4; ++j) p[j] = rowp[w0 + j];
    } else {
        // --- middle band: left / zero / right per-w ---
        int r = h - off_u;
        r = r < 0 ? 0 : (r > CROP - 1 ? CROP - 1 : r);
        #pragma unroll
        for (int j = 0; j < 4; ++j) {
            const int w = w0 + j;
            float v;
            if (w < off_l) {
                v = (w < n10_l * 10)
                    ? pl10[((size_t)base_cc * CROP + r) * 10 + (w % 10)]
                    : pl1 [ (size_t)base_cc * CROP + r];
            } else if (w >= IMAGE - orr) {
                const int wd = w - (IMAGE - orr);  // >= 0
                v = (wd < n1_r)
                    ? pr1 [ (size_t)base_cc * CROP + r]
                    : pr10[((size_t)base_cc * CROP + r) * 10 + ((wd - n1_r) % 10)];
            } else {
                v = 0.0f;
            }
            p[j] = v;
        }
    }

    const size_t off = (size_t)idx * 4;
    const float4 xv = *reinterpret_cast<const float4*>(x + off);
    float4 ov;
    ov.x = xv.x + p[0];
    ov.y = xv.y + p[1];
    ov.z = xv.z + p[2];
    ov.w = xv.w + p[3];
    *reinterpret_cast<float4*>(out + off) = ov;
}

extern "C" void kernel_launch(void* const* d_in, const int* in_sizes, int n_in,
                              void* d_out, int out_size, void* d_ws, size_t ws_size,
                              hipStream_t stream) {
    const float* x    = (const float*)d_in[0];
    const float* pu1  = (const float*)d_in[1];
    const float* pu10 = (const float*)d_in[2];
    const float* pd1  = (const float*)d_in[3];
    const float* pd10 = (const float*)d_in[4];
    const float* pl1  = (const float*)d_in[5];
    const float* pl10 = (const float*)d_in[6];
    const float* pr1  = (const float*)d_in[7];
    const float* pr10 = (const float*)d_in[8];
    const int* cam_idx   = (const int*)d_in[9];
    const int* off_right = (const int*)d_in[10];
    const int* off_down  = (const int*)d_in[11];
    float* out = (float*)d_out;

    const int total  = BATCH * 3 * TT * IMAGE * W4;   // 9,633,792 threads
    const int block  = 256;
    const int grid   = (total + block - 1) / block;   // 37,632 blocks

    prompt_add_kernel<<<grid, block, 0, stream>>>(
        x, pu1, pu10, pd1, pd10, pl1, pl10, pr1, pr10,
        cam_idx, off_right, off_down, out);
}